// Round 7
// baseline (257.873 us; speedup 1.0000x reference)
//
#include <hip/hip_runtime.h>

typedef unsigned short u16;
typedef short bf16x8 __attribute__((ext_vector_type(8)));
typedef float f32x4 __attribute__((ext_vector_type(4)));
typedef const __attribute__((address_space(1))) void* gptr_t;
typedef __attribute__((address_space(3))) void* lptr_t;

#define B_   64
#define N_   393
#define C_   768
#define H_   12
#define HD_  64
#define P_   197
#define BIAS_N 416
#define PPAD 208
#define VTP  448
#define M_KV (B_ * N_)   // 25152
#define M_PR (B_ * P_)   // 12608
#define SCALE_L2E 0.180336879f   // 0.125 * log2(e)

__device__ __forceinline__ u16 f2bf(float f) {
    unsigned u = __float_as_uint(f);
    return (u16)((u + 0x7FFFu + ((u >> 16) & 1u)) >> 16);
}
__device__ __forceinline__ unsigned cvt_pk_bf16(float lo, float hi) {
    unsigned r;
    asm("v_cvt_pk_bf16_f32 %0, %1, %2" : "=v"(r) : "v"(lo), "v"(hi));
    return r;
}
__device__ __forceinline__ float exp2_fast(float x) {
    float r;
    asm("v_exp_f32 %0, %1" : "=v"(r) : "v"(x));
    return r;
}

// ---------------------------------------------------------------------------
// fp32 -> bf16 conversion (vectorized, n % 4 == 0)
// ---------------------------------------------------------------------------
__global__ __launch_bounds__(256) void f2bf_kernel(const float* __restrict__ in,
                                                   u16* __restrict__ out, int n4) {
    int i = blockIdx.x * 256 + threadIdx.x;
    if (i < n4) {
        float4 v = ((const float4*)in)[i];
        u16 o[4] = {f2bf(v.x), f2bf(v.y), f2bf(v.z), f2bf(v.w)};
        *(uint2*)(out + i * 4) = *(uint2*)o;
    }
}

// fused conversion of wk, wv, proj_w
__global__ __launch_bounds__(256) void convw_kernel(
    const float* __restrict__ wk, const float* __restrict__ wv,
    const float* __restrict__ pw, u16* __restrict__ wkvh, u16* __restrict__ pwh) {
    int sec = blockIdx.x / 576;
    int i = (blockIdx.x % 576) * 256 + threadIdx.x;
    const float* src = sec == 0 ? wk : (sec == 1 ? wv : pw);
    u16* dst = sec == 0 ? wkvh : (sec == 1 ? wkvh + 589824 : pwh);
    float4 v = ((const float4*)src)[i];
    u16 o[4] = {f2bf(v.x), f2bf(v.y), f2bf(v.z), f2bf(v.w)};
    *(uint2*)(dst + i * 4) = *(uint2*)o;
}

// ---------------------------------------------------------------------------
// prep1: q = q_learned + pos_embed -> qh (bf16 [P][C]); lk[h][p][8] fp32
// ---------------------------------------------------------------------------
__global__ __launch_bounds__(256) void prep1_kernel(
    const float* __restrict__ q_learned, const float* __restrict__ pos_embed,
    const float* __restrict__ rpe_w, u16* __restrict__ qh, float* __restrict__ lk)
{
    __shared__ float q_s[C_];
    const int p = blockIdx.x, t = threadIdx.x;
    for (int c = t; c < C_; c += 256) {
        float v = q_learned[c] + pos_embed[p * C_ + c];
        q_s[c] = v;
        qh[p * C_ + c] = f2bf(v);
    }
    __syncthreads();
    if (t < H_ * 8) {
        int h = t >> 3, u = t & 7;
        float s = 0.f;
        #pragma unroll 8
        for (int d = 0; d < HD_; ++d)
            s = fmaf(q_s[h * HD_ + d], rpe_w[d * 8 + u], s);
        lk[(h * P_ + p) * 8 + u] = s;
    }
}

// ---------------------------------------------------------------------------
// prep2: biasT[h][j][p] = lk[h][p][bucket] * log2(e)   (pre-scaled for exp2)
// ---------------------------------------------------------------------------
__global__ __launch_bounds__(256) void prep2_kernel(
    const float* __restrict__ lk, const int* __restrict__ rp_bucket,
    float* __restrict__ biasT)
{
    int bx = blockIdx.x;
    int h = bx / N_, j = bx % N_;
    int t = threadIdx.x;
    if (t >= PPAD) return;
    int jm;
    if (j == 0) jm = 0;
    else { jm = j - 1; if (jm >= 196) jm -= 196; jm += 1; }
    float v = 0.f;
    if (t < P_) {
        int bucket = rp_bucket[t * P_ + jm];
        v = lk[(h * P_ + t) * 8 + bucket] * 1.44269504f;
    }
    biasT[((size_t)h * BIAS_N + j) * PPAD + t] = v;
}

// ---------------------------------------------------------------------------
// Templated 128x128x64 bf16 MFMA GEMM, pipelined:
// double-buffered LDS, global_load_lds staged into the NON-current buffer
// BEFORE compute (latency hidden under MFMA), ONE __syncthreads per K-tile
// (its vmcnt(0)+barrier drains the next tile). XOR-swizzle (r3-verified
// conflict-free): linear LDS dest + inverse-swizzled global source +
// swizzled ds_read (rule 21 both-sides). XCD-bijective grid swizzle.
// ---------------------------------------------------------------------------
template <bool F32OUT>
__global__ __launch_bounds__(256) void gemm_bf16(
    const u16* __restrict__ A, const u16* __restrict__ Bw,
    u16* __restrict__ Cb, float* __restrict__ Cf, const float* __restrict__ bias,
    int M, int ldc)
{
    __shared__ __align__(16) u16 As[2][128 * 64];
    __shared__ __align__(16) u16 Bs[2][128 * 64];

    const int gx = gridDim.x;
    const int nwg = gx * gridDim.y;
    const int orig = blockIdx.y * gx + blockIdx.x;
    const int xcd = orig & 7, rank = orig >> 3;
    const int q = nwg >> 3, r = nwg & 7;
    const int wgid = (xcd < r ? xcd * (q + 1) : r * (q + 1) + (xcd - r) * q) + rank;
    const int n0 = (wgid % gx) * 128;
    const int m0 = (wgid / gx) * 128;

    const int t = threadIdx.x;
    const int w = t >> 6, l = t & 63;
    const int wr = w >> 1, wc = w & 1;
    const int l15 = l & 15, lg = l >> 4;
    const int Mc = M - 1;

    // staging geometry: 4 chunks/thread per tile (A and B each), linear LDS
    // dest chunk c -> holds global slot (row = c>>3, ssrc = (c&7) ^ (row&7))
    int srow[4], sssrc[4];
    const u16* gAb[4];
    const u16* gBb[4];
    #pragma unroll
    for (int i = 0; i < 4; ++i) {
        int c = t + 256 * i;
        int row = c >> 3, s = c & 7;
        int ssrc = s ^ (row & 7);
        srow[i] = row; sssrc[i] = ssrc;
        int arow = m0 + row; if (arow > Mc) arow = Mc;
        gAb[i] = A + (size_t)arow * 768 + ssrc * 8;
        gBb[i] = Bw + (size_t)(n0 + row) * 768 + ssrc * 8;
    }

    // swizzled ds_read offsets (elem units)
    int aoff[4][2], boff[4][2];
    #pragma unroll
    for (int mf = 0; mf < 4; ++mf)
        #pragma unroll
        for (int kk = 0; kk < 2; ++kk) {
            int row = wr * 64 + mf * 16 + l15;
            int s = kk * 4 + lg;
            aoff[mf][kk] = row * 64 + ((s ^ (row & 7)) << 3);
            row = wc * 64 + mf * 16 + l15;
            boff[mf][kk] = row * 64 + ((s ^ (row & 7)) << 3);
        }

    f32x4 acc[4][4];
    #pragma unroll
    for (int i = 0; i < 4; ++i)
        #pragma unroll
        for (int j = 0; j < 4; ++j) acc[i][j] = (f32x4){0.f, 0.f, 0.f, 0.f};

    // prologue: stage tile 0 into buf 0
    #pragma unroll
    for (int i = 0; i < 4; ++i) {
        int c = t + 256 * i;
        __builtin_amdgcn_global_load_lds((gptr_t)(const void*)(gAb[i]),
                                         (lptr_t)(void*)(&As[0][c * 8]), 16, 0, 0);
        __builtin_amdgcn_global_load_lds((gptr_t)(const void*)(gBb[i]),
                                         (lptr_t)(void*)(&Bs[0][c * 8]), 16, 0, 0);
    }
    __syncthreads();   // vmcnt(0)+barrier: tile 0 resident for all waves

    for (int ks = 0; ks < 12; ++ks) {
        const int d = ks & 1;
        // stage NEXT tile into the other buffer, issued before compute
        if (ks < 11) {
            const int k0n = (ks + 1) * 64;
            #pragma unroll
            for (int i = 0; i < 4; ++i) {
                int c = t + 256 * i;
                __builtin_amdgcn_global_load_lds((gptr_t)(const void*)(gAb[i] + k0n),
                                                 (lptr_t)(void*)(&As[d ^ 1][c * 8]), 16, 0, 0);
                __builtin_amdgcn_global_load_lds((gptr_t)(const void*)(gBb[i] + k0n),
                                                 (lptr_t)(void*)(&Bs[d ^ 1][c * 8]), 16, 0, 0);
            }
        }
        // compute current tile
        #pragma unroll
        for (int kk = 0; kk < 2; ++kk) {
            bf16x8 af[4], bfr[4];
            #pragma unroll
            for (int mf = 0; mf < 4; ++mf) {
                af[mf]  = *(const bf16x8*)(&As[d][aoff[mf][kk]]);
                bfr[mf] = *(const bf16x8*)(&Bs[d][boff[mf][kk]]);
            }
            __builtin_amdgcn_s_setprio(1);
            #pragma unroll
            for (int mf = 0; mf < 4; ++mf)
                #pragma unroll
                for (int nf = 0; nf < 4; ++nf)
                    acc[mf][nf] = __builtin_amdgcn_mfma_f32_16x16x32_bf16(
                        af[mf], bfr[nf], acc[mf][nf], 0, 0, 0);
            __builtin_amdgcn_s_setprio(0);
        }
        // one barrier per K-tile: drains this wave's in-flight stage loads
        // (vmcnt(0) before s_barrier) and protects buffer reuse
        __syncthreads();
    }

    #pragma unroll
    for (int mf = 0; mf < 4; ++mf) {
        #pragma unroll
        for (int nf = 0; nf < 4; ++nf) {
            int col = n0 + wc * 64 + nf * 16 + l15;
            float bb = 0.f;
            if (F32OUT) bb = bias[col];
            #pragma unroll
            for (int rr = 0; rr < 4; ++rr) {
                int m = m0 + wr * 64 + mf * 16 + lg * 4 + rr;
                if (m < M) {
                    if (F32OUT) Cf[(size_t)m * ldc + col] = acc[mf][nf][rr] + bb;
                    else        Cb[(size_t)m * ldc + col] = f2bf(acc[mf][nf][rr]);
                }
            }
        }
    }
}

// ---------------------------------------------------------------------------
// vtrans: Vt[b][h][d][j(448)] = KV[b*393+j][768 + h*64 + d]  (j>=393 -> 0)
// ---------------------------------------------------------------------------
__global__ __launch_bounds__(256) void vtrans_kernel(const u16* __restrict__ KV,
                                                     u16* __restrict__ Vt)
{
    const int bh = blockIdx.x;
    const int b = bh / H_, h = bh % H_;
    const int t = threadIdx.x, w = t >> 6, l = t & 63;
    const int d = w * 16 + (l >> 2);
    const int c = l & 3;
    const u16* src = KV + (size_t)b * N_ * 1536 + 768 + h * HD_ + d;
    u16* dst = Vt + (size_t)(bh * HD_ + d) * VTP;
    for (int jb = 0; jb < VTP; jb += 32) {
        int j0 = jb + c * 8;
        u16 v[8];
        #pragma unroll
        for (int i = 0; i < 8; ++i) {
            int j = j0 + i;
            v[i] = (j < N_) ? src[(size_t)j * 1536] : (u16)0;
        }
        *(bf16x8*)(dst + j0) = *(bf16x8*)v;
    }
}

// ---------------------------------------------------------------------------
// attention v3 (unchanged from round 6)
// ---------------------------------------------------------------------------
__global__ __launch_bounds__(256, 2) void attn_mfma3(
    const u16* __restrict__ qh, const u16* __restrict__ KV,
    const u16* __restrict__ Vt, const float* __restrict__ biasT,
    u16* __restrict__ Obuf)
{
    __shared__ __align__(16) u16 pts[64 * 456];     // 58368 B
    __shared__ __align__(16) u16 kvs[2][64 * 64];   // 16384 B

    const int id = blockIdx.x;
    const int work = (id & 7) * 384 + (id >> 3);
    const int ptile = work & 3;
    const int rest = work >> 2;
    const int h = rest % 12;
    const int b = rest / 12;
    const int p0 = ptile * 64;

    const int t = threadIdx.x, w = t >> 6, l = t & 63;
    const int l15 = l & 15, lg = l >> 4;
    const int p0w = p0 + w * 16;

    int srow[2], sslot[2], swoff[2];
    #pragma unroll
    for (int i = 0; i < 2; ++i) {
        int c = t + 256 * i;
        srow[i] = c >> 3; sslot[i] = c & 7;
        swoff[i] = srow[i] * 64 + ((sslot[i] ^ (srow[i] & 7)) << 3);
    }

    int prow = p0w + l15; if (prow > P_ - 1) prow = P_ - 1;
    const u16* qp = qh + (size_t)prow * C_ + h * HD_ + lg * 8;
    bf16x8 qf0 = *(const bf16x8*)(qp);
    bf16x8 qf1 = *(const bf16x8*)(qp + 32);

    const u16* Kbase = KV + (size_t)b * (N_ * 1536) + h * HD_;
    const u16* Vbase = Vt + (size_t)(b * H_ + h) * (HD_ * VTP);

    f32x4 acc[7][4];
    #pragma unroll
    for (int i = 0; i < 7; ++i)
        #pragma unroll
        for (int j = 0; j < 4; ++j) acc[i][j] = (f32x4){0.f, 0.f, 0.f, 0.f};

    // ---------------- pass 1: QK^T (double-buffered, 1 barrier/tile) -------
    bf16x8 ra[2];
    #pragma unroll
    for (int i = 0; i < 2; ++i)
        ra[i] = *(const bf16x8*)(Kbase + (size_t)srow[i] * 1536 + sslot[i] * 8);
    #pragma unroll
    for (int i = 0; i < 2; ++i) *(bf16x8*)(&kvs[0][swoff[i]]) = ra[i];
    __syncthreads();

    #pragma unroll
    for (int nt = 0; nt < 7; ++nt) {
        const u16* kcur = kvs[nt & 1];
        if (nt < 6) {
            #pragma unroll
            for (int i = 0; i < 2; ++i) {
                int rn = (nt + 1) * 64 + srow[i]; if (rn > N_ - 1) rn = N_ - 1;
                ra[i] = *(const bf16x8*)(Kbase + (size_t)rn * 1536 + sslot[i] * 8);
            }
        }
        __builtin_amdgcn_s_setprio(1);
        #pragma unroll
        for (int kc = 0; kc < 2; ++kc)
            #pragma unroll
            for (int sub = 0; sub < 4; ++sub) {
                int row = sub * 16 + l15;
                bf16x8 kb = *(const bf16x8*)(kcur + row * 64 + (((kc * 4 + lg) ^ (row & 7)) << 3));
                acc[nt][sub] = __builtin_amdgcn_mfma_f32_16x16x32_bf16(
                    kc ? qf1 : qf0, kb, acc[nt][sub], 0, 0, 0);
            }
        __builtin_amdgcn_s_setprio(0);
        if (nt < 6) {
            #pragma unroll
            for (int i = 0; i < 2; ++i) *(bf16x8*)(&kvs[(nt + 1) & 1][swoff[i]]) = ra[i];
        }
        __syncthreads();
    }

    // issue V tile 0 loads now; softmax VALU hides the latency (T14)
    #pragma unroll
    for (int i = 0; i < 2; ++i)
        ra[i] = *(const bf16x8*)(Vbase + (size_t)srow[i] * VTP + sslot[i] * 8);

    // ---------------- single-pass softmax: exp2(acc*scale + bias), sum -----
    const int pcl = (p0w + lg * 4) > (PPAD - 4) ? (PPAD - 4) : (p0w + lg * 4);
    float s4[4] = {0.f, 0.f, 0.f, 0.f};
    #pragma unroll
    for (int nt = 0; nt < 7; ++nt)
        #pragma unroll
        for (int sub = 0; sub < 4; ++sub) {
            int n = nt * 64 + sub * 16 + l15;
            if (n < N_) {
                float4 b4 = *(const float4*)(biasT + ((size_t)h * BIAS_N + n) * PPAD + pcl);
                float bb[4] = {b4.x, b4.y, b4.z, b4.w};
                #pragma unroll
                for (int rr = 0; rr < 4; ++rr) {
                    float e = exp2_fast(fmaf(acc[nt][sub][rr], SCALE_L2E, bb[rr]));
                    acc[nt][sub][rr] = e;
                    s4[rr] += e;
                }
            } else {
                acc[nt][sub] = (f32x4){0.f, 0.f, 0.f, 0.f};
            }
        }
    float rinv4[4];
    #pragma unroll
    for (int rr = 0; rr < 4; ++rr) {
        float s = s4[rr];
        s += __shfl_xor(s, 1); s += __shfl_xor(s, 2);
        s += __shfl_xor(s, 4); s += __shfl_xor(s, 8);
        rinv4[rr] = 1.0f / s;
    }

    // ---------------- P -> LDS bf16 via cvt_pk ----------------
    {
        const int rowb = w * 16 + lg * 4;
        #pragma unroll
        for (int nt = 0; nt < 7; ++nt)
            #pragma unroll
            for (int sub = 0; sub < 4; ++sub) {
                int col = nt * 64 + sub * 16 + l15;
                unsigned pk01 = cvt_pk_bf16(acc[nt][sub][0] * rinv4[0],
                                            acc[nt][sub][1] * rinv4[1]);
                unsigned pk23 = cvt_pk_bf16(acc[nt][sub][2] * rinv4[2],
                                            acc[nt][sub][3] * rinv4[3]);
                pts[(rowb + 0) * 456 + col] = (u16)pk01;
                pts[(rowb + 1) * 456 + col] = (u16)(pk01 >> 16);
                pts[(rowb + 2) * 456 + col] = (u16)pk23;
                pts[(rowb + 3) * 456 + col] = (u16)(pk23 >> 16);
            }
    }
    // write V tile 0 (waits on the early global loads)
    #pragma unroll
    for (int i = 0; i < 2; ++i) *(bf16x8*)(&kvs[0][swoff[i]]) = ra[i];
    __syncthreads();

    // ---------------- pass 2: PV (double-buffered) ----------------
    f32x4 o[4];
    #pragma unroll
    for (int i = 0; i < 4; ++i) o[i] = (f32x4){0.f, 0.f, 0.f, 0.f};

    #pragma unroll
    for (int nt = 0; nt < 7; ++nt) {
        const u16* kcur = kvs[nt & 1];
        if (nt < 6) {
            #pragma unroll
            for (int i = 0; i < 2; ++i)
                ra[i] = *(const bf16x8*)(Vbase + (size_t)srow[i] * VTP + (nt + 1) * 64 + sslot[i] * 8);
        }
        __builtin_amdgcn_s_setprio(1);
        #pragma unroll
        for (int kc = 0; kc < 2; ++kc) {
            bf16x8 pa = *(const bf16x8*)(pts + (w * 16 + l15) * 456 + nt * 64 + kc * 32 + lg * 8);
            #pragma unroll
            for (int dsub = 0; dsub < 4; ++dsub) {
                int row = dsub * 16 + l15;
                bf16x8 vb = *(const bf16x8*)(kcur + row * 64 + (((kc * 4 + lg) ^ (row & 7)) << 3));
                o[dsub] = __builtin_amdgcn_mfma_f32_16x16x32_bf16(pa, vb, o[dsub], 0, 0, 0);
            }
        }
        __builtin_amdgcn_s_setprio(0);
        if (nt < 6) {
            #pragma unroll
            for (int i = 0; i < 2; ++i) *(bf16x8*)(&kvs[(nt + 1) & 1][swoff[i]]) = ra[i];
        }
        __syncthreads();
    }

    // ---------------- store ----------------
    #pragma unroll
    for (int dsub = 0; dsub < 4; ++dsub)
        #pragma unroll
        for (int rr = 0; rr < 4; ++rr) {
            int p = p0w + lg * 4 + rr;
            if (p < P_)
                Obuf[((size_t)b * P_ + p) * C_ + h * HD_ + dsub * 16 + l15] = f2bf(o[dsub][rr]);
        }
}

// ---------------------------------------------------------------------------
extern "C" void kernel_launch(void* const* d_in, const int* in_sizes, int n_in,
                              void* d_out, int out_size, void* d_ws, size_t ws_size,
                              hipStream_t stream)
{
    const float* x         = (const float*)d_in[0];
    const float* q_learned = (const float*)d_in[1];
    const float* pos_embed = (const float*)d_in[2];
    const float* wk        = (const float*)d_in[3];
    const float* wv        = (const float*)d_in[4];
    const float* rpe_w     = (const float*)d_in[5];
    const float* proj_w    = (const float*)d_in[6];
    const float* proj_b    = (const float*)d_in[7];
    const int*   rp_bucket = (const int*)d_in[8];
    float* out = (float*)d_out;

    char* ws = (char*)d_ws;
    u16*   xh    = (u16*)(ws);                        // 38,633,472 B
    u16*   wkvh  = (u16*)(ws + 38633472);             //  2,359,296 B
    u16*   pwh   = (u16*)(ws + 40992768);             //  1,179,648 B
    u16*   qh    = (u16*)(ws + 42172416);             //    302,592 B
    float* lk    = (float*)(ws + 42475008);           //     75,776 B
    float* biasT = (float*)(ws + 42550784);           //  4,153,344 B
    u16*   KV    = (u16*)(ws + 46704128);             // 77,266,944 B
    u16*   Vt    = (u16*)(ws + 123971072);            // 44,040,192 B
    u16*   Obuf  = (u16*)(ws + 168011264);            // 19,365,888 B (end ~179 MB)

    f2bf_kernel<<<(19316736 / 4 + 255) / 256, 256, 0, stream>>>(x, xh, 19316736 / 4);
    convw_kernel<<<3 * 576, 256, 0, stream>>>(wk, wv, proj_w, wkvh, pwh);

    prep1_kernel<<<P_, 256, 0, stream>>>(q_learned, pos_embed, rpe_w, qh, lk);
    prep2_kernel<<<H_ * N_, 256, 0, stream>>>(lk, rp_bucket, biasT);

    dim3 gkv(1536 / 128, (M_KV + 127) / 128);   // 12 x 197
    gemm_bf16<false><<<gkv, 256, 0, stream>>>(xh, wkvh, KV, nullptr, nullptr, M_KV, 1536);

    vtrans_kernel<<<B_ * H_, 256, 0, stream>>>(KV, Vt);

    attn_mfma3<<<3072, 256, 0, stream>>>(qh, KV, Vt, biasT, Obuf);

    dim3 gpr(768 / 128, (M_PR + 127) / 128);    // 6 x 99
    gemm_bf16<true><<<gpr, 256, 0, stream>>>(Obuf, pwh, nullptr, out, proj_b, M_PR, 768);
}

// Round 8
// 239.196 us; speedup vs baseline: 1.0781x; 1.0781x over previous
//
#include <hip/hip_runtime.h>

typedef unsigned short u16;
typedef short bf16x8 __attribute__((ext_vector_type(8)));
typedef float f32x4 __attribute__((ext_vector_type(4)));
typedef const __attribute__((address_space(1))) void* gptr_t;
typedef __attribute__((address_space(3))) void* lptr_t;

#define B_   64
#define N_   393
#define C_   768
#define H_   12
#define HD_  64
#define P_   197
#define BIAS_N 416
#define PPAD 208
#define VTP  448
#define M_KV (B_ * N_)   // 25152
#define M_PR (B_ * P_)   // 12608
#define SCALE_L2E 0.180336879f   // 0.125 * log2(e)

__device__ __forceinline__ u16 f2bf(float f) {
    unsigned u = __float_as_uint(f);
    return (u16)((u + 0x7FFFu + ((u >> 16) & 1u)) >> 16);
}
__device__ __forceinline__ unsigned cvt_pk_bf16(float lo, float hi) {
    unsigned r;
    asm("v_cvt_pk_bf16_f32 %0, %1, %2" : "=v"(r) : "v"(lo), "v"(hi));
    return r;
}
__device__ __forceinline__ float exp2_fast(float x) {
    float r;
    asm("v_exp_f32 %0, %1" : "=v"(r) : "v"(x));
    return r;
}

// ---------------------------------------------------------------------------
// conv_all: fused fp32->bf16 for x, wk, wv, proj_w (one launch)
// grid: (4829184 + 3*147456)/256 = 20592 blocks exactly
// ---------------------------------------------------------------------------
__global__ __launch_bounds__(256) void conv_all(
    const float* __restrict__ x, const float* __restrict__ wk,
    const float* __restrict__ wv, const float* __restrict__ pw,
    u16* __restrict__ xh, u16* __restrict__ wkvh, u16* __restrict__ pwh)
{
    const int XN4 = 19316736 / 4;   // 4,829,184
    const int WN4 = 589824 / 4;     // 147,456
    int i = blockIdx.x * 256 + threadIdx.x;
    const float* src; u16* dst; int off;
    if (i < XN4) { src = x; dst = xh; off = i; }
    else {
        int j = i - XN4;
        int sec = j / WN4;          // 0,1,2
        off = j - sec * WN4;
        src = sec == 0 ? wk : (sec == 1 ? wv : pw);
        dst = sec == 0 ? wkvh : (sec == 1 ? wkvh + 589824 : pwh);
    }
    float4 v = ((const float4*)src)[off];
    u16 o[4] = {f2bf(v.x), f2bf(v.y), f2bf(v.z), f2bf(v.w)};
    *(uint2*)(dst + off * 4) = *(uint2*)o;
}

// ---------------------------------------------------------------------------
// prep1: q = q_learned + pos_embed -> qh (bf16 [P][C]); lk[h][p][8] fp32
// ---------------------------------------------------------------------------
__global__ __launch_bounds__(256) void prep1_kernel(
    const float* __restrict__ q_learned, const float* __restrict__ pos_embed,
    const float* __restrict__ rpe_w, u16* __restrict__ qh, float* __restrict__ lk)
{
    __shared__ float q_s[C_];
    const int p = blockIdx.x, t = threadIdx.x;
    for (int c = t; c < C_; c += 256) {
        float v = q_learned[c] + pos_embed[p * C_ + c];
        q_s[c] = v;
        qh[p * C_ + c] = f2bf(v);
    }
    __syncthreads();
    if (t < H_ * 8) {
        int h = t >> 3, u = t & 7;
        float s = 0.f;
        #pragma unroll 8
        for (int d = 0; d < HD_; ++d)
            s = fmaf(q_s[h * HD_ + d], rpe_w[d * 8 + u], s);
        lk[(h * P_ + p) * 8 + u] = s;
    }
}

// ---------------------------------------------------------------------------
// prep2: biasT[h][j][p] = lk[h][p][bucket] * log2(e)   (pre-scaled for exp2)
// ---------------------------------------------------------------------------
__global__ __launch_bounds__(256) void prep2_kernel(
    const float* __restrict__ lk, const int* __restrict__ rp_bucket,
    float* __restrict__ biasT)
{
    int bx = blockIdx.x;
    int h = bx / N_, j = bx % N_;
    int t = threadIdx.x;
    if (t >= PPAD) return;
    int jm;
    if (j == 0) jm = 0;
    else { jm = j - 1; if (jm >= 196) jm -= 196; jm += 1; }
    float v = 0.f;
    if (t < P_) {
        int bucket = rp_bucket[t * P_ + jm];
        v = lk[(h * P_ + t) * 8 + bucket] * 1.44269504f;
    }
    biasT[((size_t)h * BIAS_N + j) * PPAD + t] = v;
}

// ---------------------------------------------------------------------------
// Templated 128x128x64 bf16 MFMA GEMM, m97 structure (round-6 known-good):
// global_load_lds(16B) into linear LDS [128][64], 2-barrier K-loop,
// bijective XCD swizzle. LDS 32KB, dense coalesced epilogue.
// ---------------------------------------------------------------------------
template <bool F32OUT>
__global__ __launch_bounds__(256) void gemm_bf16(
    const u16* __restrict__ A, const u16* __restrict__ Bw,
    u16* __restrict__ Cb, float* __restrict__ Cf, const float* __restrict__ bias,
    int M, int ldc)
{
    __shared__ __align__(16) u16 As[128 * 64];
    __shared__ __align__(16) u16 Bs[128 * 64];

    const int gx = gridDim.x;
    const int nwg = gx * gridDim.y;
    const int orig = blockIdx.y * gx + blockIdx.x;
    const int xcd = orig & 7, rank = orig >> 3;
    const int q = nwg >> 3, r = nwg & 7;
    const int wgid = (xcd < r ? xcd * (q + 1) : r * (q + 1) + (xcd - r) * q) + rank;
    const int n0 = (wgid % gx) * 128;
    const int m0 = (wgid / gx) * 128;

    const int t = threadIdx.x;
    const int w = t >> 6, l = t & 63;
    const int wr = w >> 1, wc = w & 1;
    const int l15 = l & 15, lg = l >> 4;
    const int lrow = l >> 3, lslot = l & 7;
    const int Mc = M - 1;

    f32x4 acc[4][4];
    #pragma unroll
    for (int i = 0; i < 4; ++i)
        #pragma unroll
        for (int j = 0; j < 4; ++j) acc[i][j] = (f32x4){0.f, 0.f, 0.f, 0.f};

    for (int ks = 0; ks < 12; ++ks) {
        const int k0 = ks * 64;
        if (ks) __syncthreads();          // previous tile fully consumed
        #pragma unroll
        for (int i = 0; i < 4; ++i) {
            const int rbase = w * 32 + i * 8;        // 8 rows per issue
            int arow = m0 + rbase + lrow; if (arow > Mc) arow = Mc;
            const int brow = n0 + rbase + lrow;
            const u16* ga = A  + (size_t)arow * 768 + k0 + lslot * 8;
            const u16* gb = Bw + (size_t)brow * 768 + k0 + lslot * 8;
            __builtin_amdgcn_global_load_lds((gptr_t)(const void*)ga,
                                             (lptr_t)(void*)(As + rbase * 64), 16, 0, 0);
            __builtin_amdgcn_global_load_lds((gptr_t)(const void*)gb,
                                             (lptr_t)(void*)(Bs + rbase * 64), 16, 0, 0);
        }
        __syncthreads();                  // drains vmcnt: tile resident
        #pragma unroll
        for (int kk = 0; kk < 2; ++kk) {
            bf16x8 af[4], bfr[4];
            #pragma unroll
            for (int mf = 0; mf < 4; ++mf) {
                af[mf]  = *(const bf16x8*)(As + (wr * 64 + mf * 16 + l15) * 64 + (kk * 4 + lg) * 8);
                bfr[mf] = *(const bf16x8*)(Bs + (wc * 64 + mf * 16 + l15) * 64 + (kk * 4 + lg) * 8);
            }
            #pragma unroll
            for (int mf = 0; mf < 4; ++mf)
                #pragma unroll
                for (int nf = 0; nf < 4; ++nf)
                    acc[mf][nf] = __builtin_amdgcn_mfma_f32_16x16x32_bf16(
                        af[mf], bfr[nf], acc[mf][nf], 0, 0, 0);
        }
    }

    #pragma unroll
    for (int mf = 0; mf < 4; ++mf) {
        #pragma unroll
        for (int nf = 0; nf < 4; ++nf) {
            int col = n0 + wc * 64 + nf * 16 + l15;
            float bb = 0.f;
            if (F32OUT) bb = bias[col];
            #pragma unroll
            for (int rr = 0; rr < 4; ++rr) {
                int m = m0 + wr * 64 + mf * 16 + lg * 4 + rr;
                if (m < M) {
                    if (F32OUT) Cf[(size_t)m * ldc + col] = acc[mf][nf][rr] + bb;
                    else        Cb[(size_t)m * ldc + col] = f2bf(acc[mf][nf][rr]);
                }
            }
        }
    }
}

// ---------------------------------------------------------------------------
// vtrans: Vt[b][h][d][j(448)] = KV[b*393+j][768 + h*64 + d]  (j>=393 -> 0)
// ---------------------------------------------------------------------------
__global__ __launch_bounds__(256) void vtrans_kernel(const u16* __restrict__ KV,
                                                     u16* __restrict__ Vt)
{
    const int bh = blockIdx.x;
    const int b = bh / H_, h = bh % H_;
    const int t = threadIdx.x, w = t >> 6, l = t & 63;
    const int d = w * 16 + (l >> 2);
    const int c = l & 3;
    const u16* src = KV + (size_t)b * N_ * 1536 + 768 + h * HD_ + d;
    u16* dst = Vt + (size_t)(bh * HD_ + d) * VTP;
    for (int jb = 0; jb < VTP; jb += 32) {
        int j0 = jb + c * 8;
        u16 v[8];
        #pragma unroll
        for (int i = 0; i < 8; ++i) {
            int j = j0 + i;
            v[i] = (j < N_) ? src[(size_t)j * 1536] : (u16)0;
        }
        *(bf16x8*)(dst + j0) = *(bf16x8*)v;
    }
}

// ---------------------------------------------------------------------------
// attention v4: round-6 structure + deferred rinv (PV on unnormalized P,
// normalization folded into the 16-element output epilogue).
// grid: 3072 (XCD-swizzled), block 256
// ---------------------------------------------------------------------------
__global__ __launch_bounds__(256, 2) void attn_mfma4(
    const u16* __restrict__ qh, const u16* __restrict__ KV,
    const u16* __restrict__ Vt, const float* __restrict__ biasT,
    u16* __restrict__ Obuf)
{
    __shared__ __align__(16) u16 pts[64 * 456];     // 58368 B
    __shared__ __align__(16) u16 kvs[2][64 * 64];   // 16384 B

    const int id = blockIdx.x;
    const int work = (id & 7) * 384 + (id >> 3);
    const int ptile = work & 3;
    const int rest = work >> 2;
    const int h = rest % 12;
    const int b = rest / 12;
    const int p0 = ptile * 64;

    const int t = threadIdx.x, w = t >> 6, l = t & 63;
    const int l15 = l & 15, lg = l >> 4;
    const int p0w = p0 + w * 16;

    int srow[2], sslot[2], swoff[2];
    #pragma unroll
    for (int i = 0; i < 2; ++i) {
        int c = t + 256 * i;
        srow[i] = c >> 3; sslot[i] = c & 7;
        swoff[i] = srow[i] * 64 + ((sslot[i] ^ (srow[i] & 7)) << 3);
    }

    int prow = p0w + l15; if (prow > P_ - 1) prow = P_ - 1;
    const u16* qp = qh + (size_t)prow * C_ + h * HD_ + lg * 8;
    bf16x8 qf0 = *(const bf16x8*)(qp);
    bf16x8 qf1 = *(const bf16x8*)(qp + 32);

    const u16* Kbase = KV + (size_t)b * (N_ * 1536) + h * HD_;
    const u16* Vbase = Vt + (size_t)(b * H_ + h) * (HD_ * VTP);

    f32x4 acc[7][4];
    #pragma unroll
    for (int i = 0; i < 7; ++i)
        #pragma unroll
        for (int j = 0; j < 4; ++j) acc[i][j] = (f32x4){0.f, 0.f, 0.f, 0.f};

    // ---------------- pass 1: QK^T (double-buffered, 1 barrier/tile) -------
    bf16x8 ra[2];
    #pragma unroll
    for (int i = 0; i < 2; ++i)
        ra[i] = *(const bf16x8*)(Kbase + (size_t)srow[i] * 1536 + sslot[i] * 8);
    #pragma unroll
    for (int i = 0; i < 2; ++i) *(bf16x8*)(&kvs[0][swoff[i]]) = ra[i];
    __syncthreads();

    #pragma unroll
    for (int nt = 0; nt < 7; ++nt) {
        const u16* kcur = kvs[nt & 1];
        if (nt < 6) {
            #pragma unroll
            for (int i = 0; i < 2; ++i) {
                int rn = (nt + 1) * 64 + srow[i]; if (rn > N_ - 1) rn = N_ - 1;
                ra[i] = *(const bf16x8*)(Kbase + (size_t)rn * 1536 + sslot[i] * 8);
            }
        }
        __builtin_amdgcn_s_setprio(1);
        #pragma unroll
        for (int kc = 0; kc < 2; ++kc)
            #pragma unroll
            for (int sub = 0; sub < 4; ++sub) {
                int row = sub * 16 + l15;
                bf16x8 kb = *(const bf16x8*)(kcur + row * 64 + (((kc * 4 + lg) ^ (row & 7)) << 3));
                acc[nt][sub] = __builtin_amdgcn_mfma_f32_16x16x32_bf16(
                    kc ? qf1 : qf0, kb, acc[nt][sub], 0, 0, 0);
            }
        __builtin_amdgcn_s_setprio(0);
        if (nt < 6) {
            #pragma unroll
            for (int i = 0; i < 2; ++i) *(bf16x8*)(&kvs[(nt + 1) & 1][swoff[i]]) = ra[i];
        }
        __syncthreads();
    }

    // issue V tile 0 loads now; softmax VALU hides the latency (T14)
    #pragma unroll
    for (int i = 0; i < 2; ++i)
        ra[i] = *(const bf16x8*)(Vbase + (size_t)srow[i] * VTP + sslot[i] * 8);

    // ---------------- single-pass softmax: exp2(acc*scale + bias), sum -----
    const int pcl = (p0w + lg * 4) > (PPAD - 4) ? (PPAD - 4) : (p0w + lg * 4);
    float s4[4] = {0.f, 0.f, 0.f, 0.f};
    #pragma unroll
    for (int nt = 0; nt < 7; ++nt)
        #pragma unroll
        for (int sub = 0; sub < 4; ++sub) {
            int n = nt * 64 + sub * 16 + l15;
            if (n < N_) {
                float4 b4 = *(const float4*)(biasT + ((size_t)h * BIAS_N + n) * PPAD + pcl);
                float bb[4] = {b4.x, b4.y, b4.z, b4.w};
                #pragma unroll
                for (int rr = 0; rr < 4; ++rr) {
                    float e = exp2_fast(fmaf(acc[nt][sub][rr], SCALE_L2E, bb[rr]));
                    acc[nt][sub][rr] = e;
                    s4[rr] += e;
                }
            } else {
                acc[nt][sub] = (f32x4){0.f, 0.f, 0.f, 0.f};
            }
        }
    float rinv4[4];
    #pragma unroll
    for (int rr = 0; rr < 4; ++rr) {
        float s = s4[rr];
        s += __shfl_xor(s, 1); s += __shfl_xor(s, 2);
        s += __shfl_xor(s, 4); s += __shfl_xor(s, 8);
        rinv4[rr] = 1.0f / s;
    }

    // ---------------- P (UNNORMALIZED) -> LDS bf16 via cvt_pk --------------
    {
        const int rowb = w * 16 + lg * 4;
        #pragma unroll
        for (int nt = 0; nt < 7; ++nt)
            #pragma unroll
            for (int sub = 0; sub < 4; ++sub) {
                int col = nt * 64 + sub * 16 + l15;
                unsigned pk01 = cvt_pk_bf16(acc[nt][sub][0], acc[nt][sub][1]);
                unsigned pk23 = cvt_pk_bf16(acc[nt][sub][2], acc[nt][sub][3]);
                pts[(rowb + 0) * 456 + col] = (u16)pk01;
                pts[(rowb + 1) * 456 + col] = (u16)(pk01 >> 16);
                pts[(rowb + 2) * 456 + col] = (u16)pk23;
                pts[(rowb + 3) * 456 + col] = (u16)(pk23 >> 16);
            }
    }
    // write V tile 0 (waits on the early global loads)
    #pragma unroll
    for (int i = 0; i < 2; ++i) *(bf16x8*)(&kvs[0][swoff[i]]) = ra[i];
    __syncthreads();

    // ---------------- pass 2: PV (double-buffered) ----------------
    f32x4 o[4];
    #pragma unroll
    for (int i = 0; i < 4; ++i) o[i] = (f32x4){0.f, 0.f, 0.f, 0.f};

    #pragma unroll
    for (int nt = 0; nt < 7; ++nt) {
        const u16* kcur = kvs[nt & 1];
        if (nt < 6) {
            #pragma unroll
            for (int i = 0; i < 2; ++i)
                ra[i] = *(const bf16x8*)(Vbase + (size_t)srow[i] * VTP + (nt + 1) * 64 + sslot[i] * 8);
        }
        __builtin_amdgcn_s_setprio(1);
        #pragma unroll
        for (int kc = 0; kc < 2; ++kc) {
            bf16x8 pa = *(const bf16x8*)(pts + (w * 16 + l15) * 456 + nt * 64 + kc * 32 + lg * 8);
            #pragma unroll
            for (int dsub = 0; dsub < 4; ++dsub) {
                int row = dsub * 16 + l15;
                bf16x8 vb = *(const bf16x8*)(kcur + row * 64 + (((kc * 4 + lg) ^ (row & 7)) << 3));
                o[dsub] = __builtin_amdgcn_mfma_f32_16x16x32_bf16(pa, vb, o[dsub], 0, 0, 0);
            }
        }
        __builtin_amdgcn_s_setprio(0);
        if (nt < 6) {
            #pragma unroll
            for (int i = 0; i < 2; ++i) *(bf16x8*)(&kvs[(nt + 1) & 1][swoff[i]]) = ra[i];
        }
        __syncthreads();
    }

    // ---------------- store (normalization applied here) ----------------
    #pragma unroll
    for (int dsub = 0; dsub < 4; ++dsub)
        #pragma unroll
        for (int rr = 0; rr < 4; ++rr) {
            int p = p0w + lg * 4 + rr;
            if (p < P_)
                Obuf[((size_t)b * P_ + p) * C_ + h * HD_ + dsub * 16 + l15] =
                    f2bf(o[dsub][rr] * rinv4[rr]);
        }
}

// ---------------------------------------------------------------------------
extern "C" void kernel_launch(void* const* d_in, const int* in_sizes, int n_in,
                              void* d_out, int out_size, void* d_ws, size_t ws_size,
                              hipStream_t stream)
{
    const float* x         = (const float*)d_in[0];
    const float* q_learned = (const float*)d_in[1];
    const float* pos_embed = (const float*)d_in[2];
    const float* wk        = (const float*)d_in[3];
    const float* wv        = (const float*)d_in[4];
    const float* rpe_w     = (const float*)d_in[5];
    const float* proj_w    = (const float*)d_in[6];
    const float* proj_b    = (const float*)d_in[7];
    const int*   rp_bucket = (const int*)d_in[8];
    float* out = (float*)d_out;

    char* ws = (char*)d_ws;
    u16*   xh    = (u16*)(ws);                        // 38,633,472 B
    u16*   wkvh  = (u16*)(ws + 38633472);             //  2,359,296 B
    u16*   pwh   = (u16*)(ws + 40992768);             //  1,179,648 B
    u16*   qh    = (u16*)(ws + 42172416);             //    302,592 B
    float* lk    = (float*)(ws + 42475008);           //     75,776 B
    float* biasT = (float*)(ws + 42550784);           //  4,153,344 B
    u16*   KV    = (u16*)(ws + 46704128);             // 77,266,944 B
    u16*   Vt    = (u16*)(ws + 123971072);            // 44,040,192 B
    u16*   Obuf  = (u16*)(ws + 168011264);            // 19,365,888 B (end ~179 MB)

    conv_all<<<20592, 256, 0, stream>>>(x, wk, wv, proj_w, xh, wkvh, pwh);

    prep1_kernel<<<P_, 256, 0, stream>>>(q_learned, pos_embed, rpe_w, qh, lk);
    prep2_kernel<<<H_ * N_, 256, 0, stream>>>(lk, rp_bucket, biasT);

    dim3 gkv(1536 / 128, (M_KV + 127) / 128);   // 12 x 197
    gemm_bf16<false><<<gkv, 256, 0, stream>>>(xh, wkvh, KV, nullptr, nullptr, M_KV, 1536);

    vtrans_kernel<<<B_ * H_, 256, 0, stream>>>(KV, Vt);

    attn_mfma4<<<3072, 256, 0, stream>>>(qh, KV, Vt, biasT, Obuf);

    dim3 gpr(768 / 128, (M_PR + 127) / 128);    // 6 x 99
    gemm_bf16<true><<<gpr, 256, 0, stream>>>(Obuf, pwh, nullptr, out, proj_b, M_PR, 768);
}